// Round 20
// baseline (115.555 us; speedup 1.0000x reference)
//
#include <hip/hip_runtime.h>
#include <hip/hip_bf16.h>

#define N_SEQ 2048
#define NB 8
#define DM 512
#define KD 64
#define NF 70

#define TG 512                   // table grid
#define TRANGE 6.5f              // table covers [-TRANGE, TRANGE]
#define TSCL (511.0f / 13.0f)    // (TG-1) / (2*TRANGE)
#define TOFS (6.5f * TSCL)       // 255.5

typedef float f32x4 __attribute__((ext_vector_type(4)));
typedef short v8s  __attribute__((ext_vector_type(8)));

__device__ __forceinline__ ushort f2bf(float x) {
    uint u = __float_as_uint(x);
    return (ushort)((u + 0x7FFFu + ((u >> 16) & 1u)) >> 16);
}
__device__ __forceinline__ float bf2f(ushort h) {
    return __uint_as_float(((uint)h) << 16);
}
// pack 2 f32 -> 2 bf16 in one u32 (dst.lo = lo, dst.hi = hi), RNE
__device__ __forceinline__ uint cvtpk(float lo, float hi) {
    uint r;
    asm("v_cvt_pk_bf16_f32 %0, %1, %2" : "=v"(r) : "v"(lo), "v"(hi));
    return r;
}

// ---------------------------------------------------------------------------
// Kernel A: qkv (blocks 0..511, MFMA-bound) || tbuild (blocks 512..1535,
// trans-bound) — independent work, complementary pipes, one dispatch.
// tbuild scatters g into the 4 quad slots of T4 (edge-clamped).
// ---------------------------------------------------------------------------
#define QKV_BLOCKS 512

__global__ __launch_bounds__(256) void qkvtb_kernel(
    const float* __restrict__ src, const float* __restrict__ Wq,
    const float* __restrict__ Wk, const float* __restrict__ Wv,
    ushort* __restrict__ Qh, ushort* __restrict__ Kh, ushort* __restrict__ VhT,
    const float* __restrict__ Wr, const float* __restrict__ Cc,
    float4* __restrict__ T4)
{
    __shared__ ushort sS[32][72];     // src rows (bf16), one 64-k chunk
    __shared__ ushort sW[192][72];    // Wq|Wk|Wv rows (bf16), one 64-k chunk
    int tid = threadIdx.x;

    if (blockIdx.x < QKV_BLOCKS) {
        // =================== QKV projection path ===================
        int lane = tid & 63, w = tid >> 6;
        int wr = w >> 1, wc = w & 1;
        int g = lane >> 4, ln = lane & 15;
        int row0 = blockIdx.x * 32;

        f32x4 acc[6];
#pragma unroll
        for (int t = 0; t < 6; ++t) acc[t] = {0.f, 0.f, 0.f, 0.f};

        for (int kc = 0; kc < 8; ++kc) {
            int k0 = kc * 64;
            __syncthreads();
            {   // stage src chunk: 32x64, 1 slot (8 elems) per thread
                int r = tid >> 3, c8 = (tid & 7) * 8;
                float4 f0 = *(const float4*)&src[(long)(row0 + r)*DM + k0 + c8];
                float4 f1 = *(const float4*)&src[(long)(row0 + r)*DM + k0 + c8 + 4];
                uint4 pk = make_uint4(cvtpk(f0.x, f0.y), cvtpk(f0.z, f0.w),
                                      cvtpk(f1.x, f1.y), cvtpk(f1.z, f1.w));
                *(uint4*)&sS[r][c8] = pk;
            }
            {   // stage W chunk: 192x64, 6 slots per thread
#pragma unroll
                for (int j = 0; j < 6; ++j) {
                    int slot = tid + j*256;
                    int r = slot >> 3, c8 = (slot & 7) * 8;
                    const float* Wp = (r < 64) ? Wq : (r < 128 ? Wk : Wv);
                    int rr = r & 63;
                    float4 f0 = *(const float4*)&Wp[(long)rr*DM + k0 + c8];
                    float4 f1 = *(const float4*)&Wp[(long)rr*DM + k0 + c8 + 4];
                    uint4 pk = make_uint4(cvtpk(f0.x, f0.y), cvtpk(f0.z, f0.w),
                                          cvtpk(f1.x, f1.y), cvtpk(f1.z, f1.w));
                    *(uint4*)&sW[r][c8] = pk;
                }
            }
            __syncthreads();
#pragma unroll
            for (int kw = 0; kw < 2; ++kw) {
                v8s bsrc = *(const v8s*)&sS[16*wr + ln][32*kw + 8*g];
#pragma unroll
                for (int t = 0; t < 6; ++t) {
                    v8s aw = *(const v8s*)&sW[96*wc + 16*t + ln][32*kw + 8*g];
                    acc[t] = __builtin_amdgcn_mfma_f32_16x16x32_bf16(aw, bsrc, acc[t], 0, 0, 0);
                }
            }
        }
        int n = row0 + 16*wr + ln;
        int bb = n >> 11, nn = n & 2047;
#pragma unroll
        for (int t = 0; t < 6; ++t) {
            int c0 = 96*wc + 16*t + 4*g;
            f32x4 v = acc[t];
            uint2 hp = make_uint2(cvtpk(v[0], v[1]), cvtpk(v[2], v[3]));
            if (c0 < 64) {
                *(uint2*)&Qh[(long)n*KD + c0] = hp;
            } else if (c0 < 128) {
                *(uint2*)&Kh[(long)n*KD + (c0 - 64)] = hp;
            } else {
                int kv = c0 - 128;
                VhT[((long)bb*KD + kv + 0)*N_SEQ + nn] = (ushort)(hp.x & 0xFFFFu);
                VhT[((long)bb*KD + kv + 1)*N_SEQ + nn] = (ushort)(hp.x >> 16);
                VhT[((long)bb*KD + kv + 2)*N_SEQ + nn] = (ushort)(hp.y & 0xFFFFu);
                VhT[((long)bb*KD + kv + 3)*N_SEQ + nn] = (ushort)(hp.y >> 16);
            }
        }
    } else {
        // =================== tbuild path ===================
        const float SQ2 = 1.41421356237309504880f;
        const float R2PI = 0.15915494309189533577f;
        int idx = (blockIdx.x - QKV_BLOCKS) * 256 + tid;   // TG*TG threads
        int j = idx >> 9, i = idx & (TG - 1);
        const float h = 2.0f * TRANGE / (TG - 1);
        float y = -TRANGE + j * h;
        float x = -TRANGE + i * h;
        float g = 0.f;
        for (int f = 0; f < NF; ++f) {
            float w0 = Wr[2*f] * R2PI, w1 = Wr[2*f+1] * R2PI, cf = Cc[f];
            float k = __builtin_amdgcn_fractf(fmaf(x, w0, fmaf(y, w1, 0.125f)));
            g = fmaf(cf, __builtin_amdgcn_sinf(k), g);
        }
        g *= SQ2;
        float* T = (float*)T4;
        int ix = idx;                                  // j*TG + i
        T[4*ix + 0] = g;                               // .x of (i,j)
        if (i > 0)               T[4*(ix - 1) + 1] = g;        // .y of (i-1,j)
        if (i == TG - 1)         T[4*ix + 1] = g;              // clamp
        if (j > 0)               T[4*(ix - TG) + 2] = g;       // .z of (i,j-1)
        if (j == TG - 1)         T[4*ix + 2] = g;              // clamp
        if (i > 0 && j > 0)      T[4*(ix - TG - 1) + 3] = g;   // .w of (i-1,j-1)
        if (i == TG - 1 && j > 0)         T[4*(ix - TG) + 3] = g;
        if (j == TG - 1 && i > 0)         T[4*(ix - 1) + 3] = g;
        if (i == TG - 1 && j == TG - 1)   T[4*ix + 3] = g;
    }
}

// ---------------------------------------------------------------------------
// Kernel B: f_theta STANDALONE — zero LDS so occupancy is VGPR-bound
// (~8 blocks/CU = 32 waves): max outstanding gathers for the TA-bound
// bilinear lookups. Code identical to the fat-kernel path otherwise.
// ---------------------------------------------------------------------------
__global__ __launch_bounds__(256) void ftheta_kernel(
    const float* __restrict__ bias, const float4* __restrict__ T4,
    const float* __restrict__ logp, ushort* __restrict__ Bm)
{
    int tid = threadIdx.x;
    long base = (long)blockIdx.x * 1024 + tid;
    float4 e[4];
    e[0] = ((const float4*)bias)[base];
    e[1] = ((const float4*)bias)[base + 256];
    e[2] = ((const float4*)bias)[base + 512];
    e[3] = ((const float4*)bias)[base + 768];

    // 8 independent gathers: compute all addresses, issue all loads first
    float fu[8], fv[8]; float4 q[8];
#pragma unroll
    for (int k = 0; k < 8; ++k) {
        float x = (k & 1) ? e[k>>1].z : e[k>>1].x;
        float y = (k & 1) ? e[k>>1].w : e[k>>1].y;
        float u = fmaf(x, TSCL, TOFS);
        float v = fmaf(y, TSCL, TOFS);
        u = fminf(fmaxf(u, 0.0f), 510.999f);
        v = fminf(fmaxf(v, 0.0f), 510.999f);
        int iu = (int)u, iv = (int)v;
        fu[k] = __builtin_amdgcn_fractf(u);
        fv[k] = __builtin_amdgcn_fractf(v);
        q[k] = T4[iv * TG + iu];
    }
    float gq[8];
#pragma unroll
    for (int k = 0; k < 8; ++k) {
        float t0 = fmaf(fu[k], q[k].y - q[k].x, q[k].x);
        float t1 = fmaf(fu[k], q[k].w - q[k].z, q[k].z);
        gq[k] = fmaf(fv[k], t1 - t0, t0);
    }
    float p = __expf(logp[0]);
    p = fminf(fmaxf(p, 0.5f), 3.0f);
    if (p == 1.0f) {
#pragma unroll
        for (int k = 0; k < 4; ++k)
            Bm[base + 256*k] = f2bf(__expf(-(fabsf(gq[2*k] - gq[2*k+1]) + 1e-6f)));
    } else {
#pragma unroll
        for (int k = 0; k < 4; ++k)
            Bm[base + 256*k] = f2bf(__expf(-__powf(fabsf(gq[2*k] - gq[2*k+1]) + 1e-6f, p)));
    }
}

// ---------------------------------------------------------------------------
// Kernel 3: MFMA flash attention — EXACT r19 configuration (105.0us):
// m-split 4, grid 1024, 4 blocks/CU, depth-1 B/U prefetch, online-max log2
// softmax, single-bf16 QK. Frozen.
// ---------------------------------------------------------------------------
__global__ __launch_bounds__(256, 4) void attn_mfma_kernel(
    const ushort* __restrict__ Qh, const ushort* __restrict__ Kh,
    const ushort* __restrict__ VhT, const ushort* __restrict__ Bm,
    const float* __restrict__ mult, const float* __restrict__ sp,
    ushort* __restrict__ Opart, float* __restrict__ Mp, float* __restrict__ Lp)
{
    __shared__ ushort sKh[64][72];
    __shared__ ushort sVT[64][72];              // V^T: [kv][m]
    __shared__ ushort sP[4][16][72];            // per wave: [n][m]

    int tid = threadIdx.x;
    int lane = tid & 63, w = tid >> 6;          // w in 0..3
    int g = lane >> 4, ln = lane & 15;
    int bid = blockIdx.x;
    int b = bid & 7, rest = bid >> 3, p = rest & 3, nt = rest >> 2;
    int n0 = nt * 64;

    // ---- Q (hi) into registers
    int qrow = n0 + w*16 + ln;
    long qoff = ((long)b*N_SEQ + qrow)*KD + 8*g;
    v8s qh0 = *(const v8s*)&Qh[qoff];
    v8s qh1 = *(const v8s*)&Qh[qoff + 32];

    float s  = sp[0];
    float qs = 0.125f * s * 1.44269504088896340736f;   // log2(e) folded in
    float M = -1e30f, L = 0.f;
    f32x4 accO[4];
#pragma unroll
    for (int i = 0; i < 4; ++i) accO[i] = {0.f, 0.f, 0.f, 0.f};

    long brow = (long)qrow * N_SEQ;
    long urow = ((long)b*N_SEQ + qrow) * N_SEQ;
    long vtb  = (long)b*KD*N_SEQ;
    long kbB  = (long)b*N_SEQ*KD;

    // staging slots (two uint4 per buffer per thread; 256 thr cover 64x64 bf16)
    int srow = tid >> 3, sc8 = (tid & 7) * 8;   // srow 0..31, +32 second half

    // ---- prologue: prefetch tile 0 (K/V + bias/mult)
    uint4 rKh0, rKh1, rVT0, rVT1;
    ushort4 nBq[4]; float4 nUq[4];
    {
        int m0 = p*512;
        rKh0 = *(const uint4*)&Kh[kbB + (long)(m0+srow)*KD + sc8];
        rKh1 = *(const uint4*)&Kh[kbB + (long)(m0+srow+32)*KD + sc8];
        rVT0 = *(const uint4*)&VhT[vtb + (long)srow*N_SEQ + m0 + sc8];
        rVT1 = *(const uint4*)&VhT[vtb + (long)(srow+32)*N_SEQ + m0 + sc8];
#pragma unroll
        for (int sub = 0; sub < 4; ++sub) {
            nBq[sub] = *(const ushort4*)&Bm[brow + m0 + 16*sub + 4*g];
            nUq[sub] = *(const float4*)&mult[urow + m0 + 16*sub + 4*g];
        }
    }

    for (int mt = 0; mt < 8; ++mt) {
        int m0 = p*512 + mt*64;
        __syncthreads();                     // prev compute done reading LDS
        *(uint4*)&sKh[srow][sc8]      = rKh0;
        *(uint4*)&sKh[srow + 32][sc8] = rKh1;
        *(uint4*)&sVT[srow][sc8]      = rVT0;
        *(uint4*)&sVT[srow + 32][sc8] = rVT1;
        __syncthreads();                     // LDS tile visible

        // ---- prefetch next K/V tile into regs (overlaps with compute)
        if (mt < 7) {
            int m1 = m0 + 64;
            rKh0 = *(const uint4*)&Kh[kbB + (long)(m1+srow)*KD + sc8];
            rKh1 = *(const uint4*)&Kh[kbB + (long)(m1+srow+32)*KD + sc8];
            rVT0 = *(const uint4*)&VhT[vtb + (long)srow*N_SEQ + m1 + sc8];
            rVT1 = *(const uint4*)&VhT[vtb + (long)(srow+32)*N_SEQ + m1 + sc8];
        }

        // ---- QK^T (swapped): S[sub] = Kh_sub * Qh^T
        f32x4 S[4];
#pragma unroll
        for (int i = 0; i < 4; ++i) S[i] = {0.f, 0.f, 0.f, 0.f};
        __builtin_amdgcn_s_setprio(1);
#pragma unroll
        for (int ks = 0; ks < 2; ++ks) {
            v8s qh = ks ? qh1 : qh0;
#pragma unroll
            for (int sub = 0; sub < 4; ++sub) {
                v8s kh = *(const v8s*)&sKh[16*sub + ln][32*ks + 8*g];
                S[sub] = __builtin_amdgcn_mfma_f32_16x16x32_bf16(kh, qh, S[sub], 0, 0, 0);
            }
        }
        __builtin_amdgcn_s_setprio(0);

        // ---- logits (log2 domain) + online softmax, consume nB/nU
        float lg[16]; float mx = -1e30f;
#pragma unroll
        for (int sub = 0; sub < 4; ++sub) {
            float b0 = bf2f(nBq[sub].x), b1 = bf2f(nBq[sub].y);
            float b2 = bf2f(nBq[sub].z), b3 = bf2f(nBq[sub].w);
            lg[4*sub+0] = (S[sub][0] + b0) * nUq[sub].x * qs;
            lg[4*sub+1] = (S[sub][1] + b1) * nUq[sub].y * qs;
            lg[4*sub+2] = (S[sub][2] + b2) * nUq[sub].z * qs;
            lg[4*sub+3] = (S[sub][3] + b3) * nUq[sub].w * qs;
            mx = fmaxf(mx, fmaxf(fmaxf(lg[4*sub+0], lg[4*sub+1]),
                                 fmaxf(lg[4*sub+2], lg[4*sub+3])));
        }
        // ---- prefetch next bias/mult (full iteration of latency cover)
        if (mt < 7) {
            int m1 = m0 + 64;
#pragma unroll
            for (int sub = 0; sub < 4; ++sub) {
                nBq[sub] = *(const ushort4*)&Bm[brow + m1 + 16*sub + 4*g];
                nUq[sub] = *(const float4*)&mult[urow + m1 + 16*sub + 4*g];
            }
        }
        mx = fmaxf(mx, __shfl_xor(mx, 16));
        mx = fmaxf(mx, __shfl_xor(mx, 32));
        float Mn = fmaxf(M, mx);
        float sc = __builtin_amdgcn_exp2f(M - Mn);
        float ps = 0.f;
#pragma unroll
        for (int i = 0; i < 16; ++i) {
            float e = __builtin_amdgcn_exp2f(lg[i] - Mn);
            lg[i] = e; ps += e;
        }
        ps += __shfl_xor(ps, 16);
        ps += __shfl_xor(ps, 32);
        L = L * sc + ps; M = Mn;

        // ---- P -> bf16 in LDS via cvt_pk (wave-private, no barrier needed)
#pragma unroll
        for (int sub = 0; sub < 4; ++sub) {
            uint2 pk = make_uint2(cvtpk(lg[4*sub+0], lg[4*sub+1]),
                                  cvtpk(lg[4*sub+2], lg[4*sub+3]));
            *(uint2*)&sP[w][ln][16*sub + 4*g] = pk;
        }

        // ---- rescale O, then PV: O^T += V^T * P^T
#pragma unroll
        for (int i = 0; i < 4; ++i) accO[i] *= sc;
        __builtin_amdgcn_s_setprio(1);
#pragma unroll
        for (int ks = 0; ks < 2; ++ks) {
            v8s pp = *(const v8s*)&sP[w][ln][32*ks + 8*g];
#pragma unroll
            for (int sub = 0; sub < 4; ++sub) {
                v8s vh = *(const v8s*)&sVT[16*sub + ln][32*ks + 8*g];
                accO[sub] = __builtin_amdgcn_mfma_f32_16x16x32_bf16(vh, pp, accO[sub], 0, 0, 0);
            }
        }
        __builtin_amdgcn_s_setprio(0);
    }

    // ---- epilogue: unnormalized partial O^T (bf16) + (M, L)
    long ob = ((long)bid*64 + (w*16 + ln)) * 64;
#pragma unroll
    for (int sub = 0; sub < 4; ++sub) {
        uint2 pk = make_uint2(cvtpk(accO[sub][0], accO[sub][1]),
                              cvtpk(accO[sub][2], accO[sub][3]));
        *(uint2*)&Opart[ob + 16*sub + 4*g] = pk;
    }
    if (g == 0) {
        Mp[bid*64 + w*16 + ln] = M;
        Lp[bid*64 + w*16 + ln] = L;
    }
}

// ---------------------------------------------------------------------------
// Kernel 4: merge the four m-quarters (flash combine, log2 domain) + normalize.
// ---------------------------------------------------------------------------
__global__ __launch_bounds__(256) void combine_kernel(
    const ushort* __restrict__ Opart, const float* __restrict__ Mp,
    const float* __restrict__ Lp, float* __restrict__ out)
{
    int idx = blockIdx.x * 256 + threadIdx.x;   // 262144 float4-quads
    int kq = idx & 15;
    int row = idx >> 4;                          // b*2048 + n
    int b = row >> 11, n = row & 2047;
    int nt = n >> 6, r = n & 63;
    int bid0 = ((nt*4) << 3) | b;                // +8 per quarter
    float Mq[4], Lq[4];
#pragma unroll
    for (int p = 0; p < 4; ++p) {
        Mq[p] = Mp[(bid0 + 8*p)*64 + r];
        Lq[p] = Lp[(bid0 + 8*p)*64 + r];
    }
    float Mx = fmaxf(fmaxf(Mq[0], Mq[1]), fmaxf(Mq[2], Mq[3]));
    float4 acc = make_float4(0.f, 0.f, 0.f, 0.f);
    float Ls = 0.f;
#pragma unroll
    for (int p = 0; p < 4; ++p) {
        float e = __builtin_amdgcn_exp2f(Mq[p] - Mx);   // log2-domain M's
        Ls += Lq[p] * e;
        ushort4 o = *(const ushort4*)&Opart[((long)(bid0 + 8*p)*64 + r)*64 + 4*kq];
        acc.x = fmaf(e, bf2f(o.x), acc.x);
        acc.y = fmaf(e, bf2f(o.y), acc.y);
        acc.z = fmaf(e, bf2f(o.z), acc.z);
        acc.w = fmaf(e, bf2f(o.w), acc.w);
    }
    float inv = 1.0f / Ls;
    float4 o;
    o.x = acc.x * inv; o.y = acc.y * inv;
    o.z = acc.z * inv; o.w = acc.w * inv;
    *(float4*)&out[(long)row*64 + 4*kq] = o;
}

// ---------------------------------------------------------------------------
extern "C" void kernel_launch(void* const* d_in, const int* in_sizes, int n_in,
                              void* d_out, int out_size, void* d_ws, size_t ws_size,
                              hipStream_t stream) {
    const float* src  = (const float*)d_in[0];
    const float* bias = (const float*)d_in[1];
    const float* mult = (const float*)d_in[2];
    const float* Wr   = (const float*)d_in[3];
    const float* Cc   = (const float*)d_in[4];
    const float* logp = (const float*)d_in[5];
    const float* Wq   = (const float*)d_in[6];
    const float* Wk   = (const float*)d_in[7];
    const float* Wv   = (const float*)d_in[8];
    const float* sp   = (const float*)d_in[9];
    float* outp = (float*)d_out;

    const size_t QKV_E = (size_t)NB * N_SEQ * KD;       // 1048576
    ushort* wsu = (ushort*)d_ws;
    ushort* Bm  = wsu;                                  // 8.39 MB
    ushort* Qh  = wsu + (size_t)N_SEQ * N_SEQ;
    ushort* Kh  = Qh + QKV_E;
    ushort* VhT = Kh + QKV_E;
    ushort* Opart = VhT + QKV_E;                        // 1024*64*64 bf16 = 8.39 MB
    float* Mp = (float*)(Opart + (size_t)1024 * 64 * 64);
    float* Lp = Mp + (size_t)1024 * 64;
    float4* T4 = (float4*)(Lp + (size_t)1024 * 64);     // 4 MB

    // kernel A: qkv (512 blocks) || tbuild (1024 blocks)
    qkvtb_kernel<<<QKV_BLOCKS + (TG*TG)/256, 256, 0, stream>>>(
        src, Wq, Wk, Wv, Qh, Kh, VhT, Wr, Cc, T4);
    // kernel B: ftheta standalone (no LDS -> 8 blocks/CU occupancy)
    ftheta_kernel<<<4096, 256, 0, stream>>>(bias, T4, logp, Bm);
    attn_mfma_kernel<<<1024, 256, 0, stream>>>(Qh, Kh, VhT, Bm, mult, sp,
                                               Opart, Mp, Lp);
    combine_kernel<<<1024, 256, 0, stream>>>(Opart, Mp, Lp, outp);
}

// Round 21
// 104.516 us; speedup vs baseline: 1.1056x; 1.1056x over previous
//
#include <hip/hip_runtime.h>
#include <hip/hip_bf16.h>

#define N_SEQ 2048
#define NB 8
#define DM 512
#define KD 64
#define NF 70

#define TG 512                   // table grid
#define TRANGE 6.5f              // table covers [-TRANGE, TRANGE]
#define TSCL (511.0f / 13.0f)    // (TG-1) / (2*TRANGE)
#define TOFS (6.5f * TSCL)       // 255.5

typedef float f32x4 __attribute__((ext_vector_type(4)));
typedef short v8s  __attribute__((ext_vector_type(8)));

__device__ __forceinline__ ushort f2bf(float x) {
    uint u = __float_as_uint(x);
    return (ushort)((u + 0x7FFFu + ((u >> 16) & 1u)) >> 16);
}
__device__ __forceinline__ float bf2f(ushort h) {
    return __uint_as_float(((uint)h) << 16);
}
// pack 2 f32 -> 2 bf16 in one u32 (dst.lo = lo, dst.hi = hi), RNE
__device__ __forceinline__ uint cvtpk(float lo, float hi) {
    uint r;
    asm("v_cvt_pk_bf16_f32 %0, %1, %2" : "=v"(r) : "v"(lo), "v"(hi));
    return r;
}

// ---------------------------------------------------------------------------
// Kernel 0: build quad table directly (scatter into the 4 quad slots).
// T4[j][i] = ( g[j][i], g[j][i+1], g[j+1][i], g[j+1][i+1] )   (clamped)
// ---------------------------------------------------------------------------
__global__ __launch_bounds__(256) void tbuild_kernel(
    const float* __restrict__ Wr, const float* __restrict__ Cc,
    float4* __restrict__ T4)
{
    const float SQ2 = 1.41421356237309504880f;
    const float R2PI = 0.15915494309189533577f;
    int idx = blockIdx.x * 256 + threadIdx.x;      // TG*TG threads
    int j = idx >> 9, i = idx & (TG - 1);
    const float h = 2.0f * TRANGE / (TG - 1);
    float y = -TRANGE + j * h;
    float x = -TRANGE + i * h;
    float g = 0.f;
    for (int f = 0; f < NF; ++f) {
        float w0 = Wr[2*f] * R2PI, w1 = Wr[2*f+1] * R2PI, cf = Cc[f];
        float k = __builtin_amdgcn_fractf(fmaf(x, w0, fmaf(y, w1, 0.125f)));
        g = fmaf(cf, __builtin_amdgcn_sinf(k), g);
    }
    g *= SQ2;
    float* T = (float*)T4;
    int ix = idx;                                  // j*TG + i
    T[4*ix + 0] = g;                               // .x of (i,j)
    if (i > 0)               T[4*(ix - 1) + 1] = g;        // .y of (i-1,j)
    if (i == TG - 1)         T[4*ix + 1] = g;              // clamp
    if (j > 0)               T[4*(ix - TG) + 2] = g;       // .z of (i,j-1)
    if (j == TG - 1)         T[4*ix + 2] = g;              // clamp
    if (i > 0 && j > 0)      T[4*(ix - TG - 1) + 3] = g;   // .w of (i-1,j-1)
    if (i == TG - 1 && j > 0)         T[4*(ix - TG) + 3] = g;
    if (j == TG - 1 && i > 0)         T[4*(ix - 1) + 3] = g;
    if (i == TG - 1 && j == TG - 1)   T[4*ix + 3] = g;
}

// ---------------------------------------------------------------------------
// Fat kernel (r19 configuration): blocks 0..511 do the QKV projection
// (MFMA, 32 rows/block, Q/K emitted hi-only); blocks 512..4607 do f_theta.
// ---------------------------------------------------------------------------
#define QKV_BLOCKS 512

__global__ __launch_bounds__(256) void fat_kernel(
    const float* __restrict__ src, const float* __restrict__ Wq,
    const float* __restrict__ Wk, const float* __restrict__ Wv,
    ushort* __restrict__ Qh, ushort* __restrict__ Kh, ushort* __restrict__ VhT,
    const float* __restrict__ bias, const float4* __restrict__ T4,
    const float* __restrict__ logp, ushort* __restrict__ Bm)
{
    __shared__ ushort sS[32][72];     // src rows (bf16), one 64-k chunk
    __shared__ ushort sW[192][72];    // Wq|Wk|Wv rows (bf16), one 64-k chunk
    int tid = threadIdx.x;

    if (blockIdx.x < QKV_BLOCKS) {
        // =================== QKV projection path ===================
        int lane = tid & 63, w = tid >> 6;
        int wr = w >> 1, wc = w & 1;
        int g = lane >> 4, ln = lane & 15;
        int row0 = blockIdx.x * 32;

        f32x4 acc[6];
#pragma unroll
        for (int t = 0; t < 6; ++t) acc[t] = {0.f, 0.f, 0.f, 0.f};

        for (int kc = 0; kc < 8; ++kc) {
            int k0 = kc * 64;
            __syncthreads();
            {   // stage src chunk: 32x64, 1 slot (8 elems) per thread
                int r = tid >> 3, c8 = (tid & 7) * 8;
                float4 f0 = *(const float4*)&src[(long)(row0 + r)*DM + k0 + c8];
                float4 f1 = *(const float4*)&src[(long)(row0 + r)*DM + k0 + c8 + 4];
                uint4 pk = make_uint4(cvtpk(f0.x, f0.y), cvtpk(f0.z, f0.w),
                                      cvtpk(f1.x, f1.y), cvtpk(f1.z, f1.w));
                *(uint4*)&sS[r][c8] = pk;
            }
            {   // stage W chunk: 192x64, 6 slots per thread
#pragma unroll
                for (int j = 0; j < 6; ++j) {
                    int slot = tid + j*256;
                    int r = slot >> 3, c8 = (slot & 7) * 8;
                    const float* Wp = (r < 64) ? Wq : (r < 128 ? Wk : Wv);
                    int rr = r & 63;
                    float4 f0 = *(const float4*)&Wp[(long)rr*DM + k0 + c8];
                    float4 f1 = *(const float4*)&Wp[(long)rr*DM + k0 + c8 + 4];
                    uint4 pk = make_uint4(cvtpk(f0.x, f0.y), cvtpk(f0.z, f0.w),
                                          cvtpk(f1.x, f1.y), cvtpk(f1.z, f1.w));
                    *(uint4*)&sW[r][c8] = pk;
                }
            }
            __syncthreads();
#pragma unroll
            for (int kw = 0; kw < 2; ++kw) {
                v8s bsrc = *(const v8s*)&sS[16*wr + ln][32*kw + 8*g];
#pragma unroll
                for (int t = 0; t < 6; ++t) {
                    v8s aw = *(const v8s*)&sW[96*wc + 16*t + ln][32*kw + 8*g];
                    acc[t] = __builtin_amdgcn_mfma_f32_16x16x32_bf16(aw, bsrc, acc[t], 0, 0, 0);
                }
            }
        }
        int n = row0 + 16*wr + ln;
        int bb = n >> 11, nn = n & 2047;
#pragma unroll
        for (int t = 0; t < 6; ++t) {
            int c0 = 96*wc + 16*t + 4*g;
            f32x4 v = acc[t];
            uint2 hp = make_uint2(cvtpk(v[0], v[1]), cvtpk(v[2], v[3]));
            if (c0 < 64) {
                *(uint2*)&Qh[(long)n*KD + c0] = hp;
            } else if (c0 < 128) {
                *(uint2*)&Kh[(long)n*KD + (c0 - 64)] = hp;
            } else {
                int kv = c0 - 128;
                VhT[((long)bb*KD + kv + 0)*N_SEQ + nn] = (ushort)(hp.x & 0xFFFFu);
                VhT[((long)bb*KD + kv + 1)*N_SEQ + nn] = (ushort)(hp.x >> 16);
                VhT[((long)bb*KD + kv + 2)*N_SEQ + nn] = (ushort)(hp.y & 0xFFFFu);
                VhT[((long)bb*KD + kv + 3)*N_SEQ + nn] = (ushort)(hp.y >> 16);
            }
        }
    } else {
        // =================== f_theta path (4 elements/thread) ===================
        long base = (long)(blockIdx.x - QKV_BLOCKS) * 1024 + tid;
        float4 e[4];
        e[0] = ((const float4*)bias)[base];
        e[1] = ((const float4*)bias)[base + 256];
        e[2] = ((const float4*)bias)[base + 512];
        e[3] = ((const float4*)bias)[base + 768];

        // 8 independent gathers: compute all addresses, issue all loads first
        float fu[8], fv[8]; float4 q[8];
#pragma unroll
        for (int k = 0; k < 8; ++k) {
            float x = (k & 1) ? e[k>>1].z : e[k>>1].x;
            float y = (k & 1) ? e[k>>1].w : e[k>>1].y;
            float u = fmaf(x, TSCL, TOFS);
            float v = fmaf(y, TSCL, TOFS);
            u = fminf(fmaxf(u, 0.0f), 510.999f);
            v = fminf(fmaxf(v, 0.0f), 510.999f);
            int iu = (int)u, iv = (int)v;
            fu[k] = __builtin_amdgcn_fractf(u);
            fv[k] = __builtin_amdgcn_fractf(v);
            q[k] = T4[iv * TG + iu];
        }
        float gq[8];
#pragma unroll
        for (int k = 0; k < 8; ++k) {
            float t0 = fmaf(fu[k], q[k].y - q[k].x, q[k].x);
            float t1 = fmaf(fu[k], q[k].w - q[k].z, q[k].z);
            gq[k] = fmaf(fv[k], t1 - t0, t0);
        }
        float p = __expf(logp[0]);
        p = fminf(fmaxf(p, 0.5f), 3.0f);
        if (p == 1.0f) {
#pragma unroll
            for (int k = 0; k < 4; ++k)
                Bm[base + 256*k] = f2bf(__expf(-(fabsf(gq[2*k] - gq[2*k+1]) + 1e-6f)));
        } else {
#pragma unroll
            for (int k = 0; k < 4; ++k)
                Bm[base + 256*k] = f2bf(__expf(-__powf(fabsf(gq[2*k] - gq[2*k+1]) + 1e-6f, p)));
        }
    }
}

// ---------------------------------------------------------------------------
// Kernel 3: MFMA flash attention — EXACT r19 configuration (105.0us):
// m-split 4, grid 1024, 4 blocks/CU, depth-1 B/U prefetch, online-max log2
// softmax, single-bf16 QK. Frozen.
// ---------------------------------------------------------------------------
__global__ __launch_bounds__(256, 4) void attn_mfma_kernel(
    const ushort* __restrict__ Qh, const ushort* __restrict__ Kh,
    const ushort* __restrict__ VhT, const ushort* __restrict__ Bm,
    const float* __restrict__ mult, const float* __restrict__ sp,
    ushort* __restrict__ Opart, float* __restrict__ Mp, float* __restrict__ Lp)
{
    __shared__ ushort sKh[64][72];
    __shared__ ushort sVT[64][72];              // V^T: [kv][m]
    __shared__ ushort sP[4][16][72];            // per wave: [n][m]

    int tid = threadIdx.x;
    int lane = tid & 63, w = tid >> 6;          // w in 0..3
    int g = lane >> 4, ln = lane & 15;
    int bid = blockIdx.x;
    int b = bid & 7, rest = bid >> 3, p = rest & 3, nt = rest >> 2;
    int n0 = nt * 64;

    // ---- Q (hi) into registers
    int qrow = n0 + w*16 + ln;
    long qoff = ((long)b*N_SEQ + qrow)*KD + 8*g;
    v8s qh0 = *(const v8s*)&Qh[qoff];
    v8s qh1 = *(const v8s*)&Qh[qoff + 32];

    float s  = sp[0];
    float qs = 0.125f * s * 1.44269504088896340736f;   // log2(e) folded in
    float M = -1e30f, L = 0.f;
    f32x4 accO[4];
#pragma unroll
    for (int i = 0; i < 4; ++i) accO[i] = {0.f, 0.f, 0.f, 0.f};

    long brow = (long)qrow * N_SEQ;
    long urow = ((long)b*N_SEQ + qrow) * N_SEQ;
    long vtb  = (long)b*KD*N_SEQ;
    long kbB  = (long)b*N_SEQ*KD;

    // staging slots (two uint4 per buffer per thread; 256 thr cover 64x64 bf16)
    int srow = tid >> 3, sc8 = (tid & 7) * 8;   // srow 0..31, +32 second half

    // ---- prologue: prefetch tile 0 (K/V + bias/mult)
    uint4 rKh0, rKh1, rVT0, rVT1;
    ushort4 nBq[4]; float4 nUq[4];
    {
        int m0 = p*512;
        rKh0 = *(const uint4*)&Kh[kbB + (long)(m0+srow)*KD + sc8];
        rKh1 = *(const uint4*)&Kh[kbB + (long)(m0+srow+32)*KD + sc8];
        rVT0 = *(const uint4*)&VhT[vtb + (long)srow*N_SEQ + m0 + sc8];
        rVT1 = *(const uint4*)&VhT[vtb + (long)(srow+32)*N_SEQ + m0 + sc8];
#pragma unroll
        for (int sub = 0; sub < 4; ++sub) {
            nBq[sub] = *(const ushort4*)&Bm[brow + m0 + 16*sub + 4*g];
            nUq[sub] = *(const float4*)&mult[urow + m0 + 16*sub + 4*g];
        }
    }

    for (int mt = 0; mt < 8; ++mt) {
        int m0 = p*512 + mt*64;
        __syncthreads();                     // prev compute done reading LDS
        *(uint4*)&sKh[srow][sc8]      = rKh0;
        *(uint4*)&sKh[srow + 32][sc8] = rKh1;
        *(uint4*)&sVT[srow][sc8]      = rVT0;
        *(uint4*)&sVT[srow + 32][sc8] = rVT1;
        __syncthreads();                     // LDS tile visible

        // ---- prefetch next K/V tile into regs (overlaps with compute)
        if (mt < 7) {
            int m1 = m0 + 64;
            rKh0 = *(const uint4*)&Kh[kbB + (long)(m1+srow)*KD + sc8];
            rKh1 = *(const uint4*)&Kh[kbB + (long)(m1+srow+32)*KD + sc8];
            rVT0 = *(const uint4*)&VhT[vtb + (long)srow*N_SEQ + m1 + sc8];
            rVT1 = *(const uint4*)&VhT[vtb + (long)(srow+32)*N_SEQ + m1 + sc8];
        }

        // ---- QK^T (swapped): S[sub] = Kh_sub * Qh^T
        f32x4 S[4];
#pragma unroll
        for (int i = 0; i < 4; ++i) S[i] = {0.f, 0.f, 0.f, 0.f};
        __builtin_amdgcn_s_setprio(1);
#pragma unroll
        for (int ks = 0; ks < 2; ++ks) {
            v8s qh = ks ? qh1 : qh0;
#pragma unroll
            for (int sub = 0; sub < 4; ++sub) {
                v8s kh = *(const v8s*)&sKh[16*sub + ln][32*ks + 8*g];
                S[sub] = __builtin_amdgcn_mfma_f32_16x16x32_bf16(kh, qh, S[sub], 0, 0, 0);
            }
        }
        __builtin_amdgcn_s_setprio(0);

        // ---- logits (log2 domain) + online softmax, consume nB/nU
        float lg[16]; float mx = -1e30f;
#pragma unroll
        for (int sub = 0; sub < 4; ++sub) {
            float b0 = bf2f(nBq[sub].x), b1 = bf2f(nBq[sub].y);
            float b2 = bf2f(nBq[sub].z), b3 = bf2f(nBq[sub].w);
            lg[4*sub+0] = (S[sub][0] + b0) * nUq[sub].x * qs;
            lg[4*sub+1] = (S[sub][1] + b1) * nUq[sub].y * qs;
            lg[4*sub+2] = (S[sub][2] + b2) * nUq[sub].z * qs;
            lg[4*sub+3] = (S[sub][3] + b3) * nUq[sub].w * qs;
            mx = fmaxf(mx, fmaxf(fmaxf(lg[4*sub+0], lg[4*sub+1]),
                                 fmaxf(lg[4*sub+2], lg[4*sub+3])));
        }
        // ---- prefetch next bias/mult (full iteration of latency cover)
        if (mt < 7) {
            int m1 = m0 + 64;
#pragma unroll
            for (int sub = 0; sub < 4; ++sub) {
                nBq[sub] = *(const ushort4*)&Bm[brow + m1 + 16*sub + 4*g];
                nUq[sub] = *(const float4*)&mult[urow + m1 + 16*sub + 4*g];
            }
        }
        mx = fmaxf(mx, __shfl_xor(mx, 16));
        mx = fmaxf(mx, __shfl_xor(mx, 32));
        float Mn = fmaxf(M, mx);
        float sc = __builtin_amdgcn_exp2f(M - Mn);
        float ps = 0.f;
#pragma unroll
        for (int i = 0; i < 16; ++i) {
            float e = __builtin_amdgcn_exp2f(lg[i] - Mn);
            lg[i] = e; ps += e;
        }
        ps += __shfl_xor(ps, 16);
        ps += __shfl_xor(ps, 32);
        L = L * sc + ps; M = Mn;

        // ---- P -> bf16 in LDS via cvt_pk (wave-private, no barrier needed)
#pragma unroll
        for (int sub = 0; sub < 4; ++sub) {
            uint2 pk = make_uint2(cvtpk(lg[4*sub+0], lg[4*sub+1]),
                                  cvtpk(lg[4*sub+2], lg[4*sub+3]));
            *(uint2*)&sP[w][ln][16*sub + 4*g] = pk;
        }

        // ---- rescale O, then PV: O^T += V^T * P^T
#pragma unroll
        for (int i = 0; i < 4; ++i) accO[i] *= sc;
        __builtin_amdgcn_s_setprio(1);
#pragma unroll
        for (int ks = 0; ks < 2; ++ks) {
            v8s pp = *(const v8s*)&sP[w][ln][32*ks + 8*g];
#pragma unroll
            for (int sub = 0; sub < 4; ++sub) {
                v8s vh = *(const v8s*)&sVT[16*sub + ln][32*ks + 8*g];
                accO[sub] = __builtin_amdgcn_mfma_f32_16x16x32_bf16(vh, pp, accO[sub], 0, 0, 0);
            }
        }
        __builtin_amdgcn_s_setprio(0);
    }

    // ---- epilogue: unnormalized partial O^T (bf16) + (M, L)
    long ob = ((long)bid*64 + (w*16 + ln)) * 64;
#pragma unroll
    for (int sub = 0; sub < 4; ++sub) {
        uint2 pk = make_uint2(cvtpk(accO[sub][0], accO[sub][1]),
                              cvtpk(accO[sub][2], accO[sub][3]));
        *(uint2*)&Opart[ob + 16*sub + 4*g] = pk;
    }
    if (g == 0) {
        Mp[bid*64 + w*16 + ln] = M;
        Lp[bid*64 + w*16 + ln] = L;
    }
}

// ---------------------------------------------------------------------------
// Kernel 4: merge the four m-quarters (flash combine, log2 domain) + normalize.
// ---------------------------------------------------------------------------
__global__ __launch_bounds__(256) void combine_kernel(
    const ushort* __restrict__ Opart, const float* __restrict__ Mp,
    const float* __restrict__ Lp, float* __restrict__ out)
{
    int idx = blockIdx.x * 256 + threadIdx.x;   // 262144 float4-quads
    int kq = idx & 15;
    int row = idx >> 4;                          // b*2048 + n
    int b = row >> 11, n = row & 2047;
    int nt = n >> 6, r = n & 63;
    int bid0 = ((nt*4) << 3) | b;                // +8 per quarter
    float Mq[4], Lq[4];
#pragma unroll
    for (int p = 0; p < 4; ++p) {
        Mq[p] = Mp[(bid0 + 8*p)*64 + r];
        Lq[p] = Lp[(bid0 + 8*p)*64 + r];
    }
    float Mx = fmaxf(fmaxf(Mq[0], Mq[1]), fmaxf(Mq[2], Mq[3]));
    float4 acc = make_float4(0.f, 0.f, 0.f, 0.f);
    float Ls = 0.f;
#pragma unroll
    for (int p = 0; p < 4; ++p) {
        float e = __builtin_amdgcn_exp2f(Mq[p] - Mx);   // log2-domain M's
        Ls += Lq[p] * e;
        ushort4 o = *(const ushort4*)&Opart[((long)(bid0 + 8*p)*64 + r)*64 + 4*kq];
        acc.x = fmaf(e, bf2f(o.x), acc.x);
        acc.y = fmaf(e, bf2f(o.y), acc.y);
        acc.z = fmaf(e, bf2f(o.z), acc.z);
        acc.w = fmaf(e, bf2f(o.w), acc.w);
    }
    float inv = 1.0f / Ls;
    float4 o;
    o.x = acc.x * inv; o.y = acc.y * inv;
    o.z = acc.z * inv; o.w = acc.w * inv;
    *(float4*)&out[(long)row*64 + 4*kq] = o;
}

// ---------------------------------------------------------------------------
extern "C" void kernel_launch(void* const* d_in, const int* in_sizes, int n_in,
                              void* d_out, int out_size, void* d_ws, size_t ws_size,
                              hipStream_t stream) {
    const float* src  = (const float*)d_in[0];
    const float* bias = (const float*)d_in[1];
    const float* mult = (const float*)d_in[2];
    const float* Wr   = (const float*)d_in[3];
    const float* Cc   = (const float*)d_in[4];
    const float* logp = (const float*)d_in[5];
    const float* Wq   = (const float*)d_in[6];
    const float* Wk   = (const float*)d_in[7];
    const float* Wv   = (const float*)d_in[8];
    const float* sp   = (const float*)d_in[9];
    float* outp = (float*)d_out;

    const size_t QKV_E = (size_t)NB * N_SEQ * KD;       // 1048576
    ushort* wsu = (ushort*)d_ws;
    ushort* Bm  = wsu;                                  // 8.39 MB
    ushort* Qh  = wsu + (size_t)N_SEQ * N_SEQ;
    ushort* Kh  = Qh + QKV_E;
    ushort* VhT = Kh + QKV_E;
    ushort* Opart = VhT + QKV_E;                        // 1024*64*64 bf16 = 8.39 MB
    float* Mp = (float*)(Opart + (size_t)1024 * 64 * 64);
    float* Lp = Mp + (size_t)1024 * 64;
    float4* T4 = (float4*)(Lp + (size_t)1024 * 64);     // 4 MB

    tbuild_kernel<<<(TG*TG)/256, 256, 0, stream>>>(Wr, Cc, T4);
    // fat kernel: 512 qkv blocks (32 rows each) + 4096 ftheta blocks
    fat_kernel<<<QKV_BLOCKS + 4096, 256, 0, stream>>>(
        src, Wq, Wk, Wv, Qh, Kh, VhT, bias, T4, logp, Bm);
    attn_mfma_kernel<<<1024, 256, 0, stream>>>(Qh, Kh, VhT, Bm, mult, sp,
                                               Opart, Mp, Lp);
    combine_kernel<<<1024, 256, 0, stream>>>(Opart, Mp, Lp, outp);
}